// Round 4
// baseline (881.216 us; speedup 1.0000x reference)
//
#include <hip/hip_runtime.h>

typedef unsigned short u16;
typedef unsigned int u32;
typedef u16 u16x4 __attribute__((ext_vector_type(4)));
typedef u16 u16x8 __attribute__((ext_vector_type(8)));
typedef short bf16x8 __attribute__((ext_vector_type(8)));
typedef float f32x4 __attribute__((ext_vector_type(4)));

static __device__ __forceinline__ u16 f2bf(float f) {
  union { float f; unsigned u; } v; v.f = f;
  unsigned r = v.u + 0x7FFFu + ((v.u >> 16) & 1u);
  return (u16)(r >> 16);
}

// async global->LDS, 16B per lane (dest must be linear: wave base + lane*16)
static __device__ __forceinline__ void gld_lds16(const u16* g, u16* l) {
  __builtin_amdgcn_global_load_lds(
      (const __attribute__((address_space(1))) u32*)g,
      (__attribute__((address_space(3))) u32*)l, 16, 0, 0);
}

// Problem constants: B=32, L=512, E=1024, H=8, D=128, OUT=1024
// score: (H*B, 512, 512) head-major.  ctx: (B, 512, H*128)

// ---------------------------------------------------------------------------
// m97-style bf16 GEMM: C = A @ Bt^T.  A: 16384x1024 bf16 row-major,
// Bt: 1024x1024 bf16 row-major.  Tile 128x128, BK=64, 4 waves (2x2).
// Linear LDS + global_load_lds width-16 staging.
// ---------------------------------------------------------------------------
template<bool OUT_F32, bool WRITE_T, bool BIAS>
__global__ __launch_bounds__(256)
void gemm_bt16(const u16* __restrict__ A, const u16* __restrict__ Bt,
               void* __restrict__ C_, u16* __restrict__ Ct,
               const float* __restrict__ bias)
{
  constexpr int LD = 1024;
  __shared__ __align__(16) u16 As[128 * 64];
  __shared__ __align__(16) u16 Bs[128 * 64];

  const int tid  = threadIdx.x;
  const int lane = tid & 63;
  const int w    = tid >> 6;
  const int wr   = w >> 1, wc = w & 1;
  const int brow = blockIdx.y * 128;
  const int bcol = blockIdx.x * 128;
  const int kgrp = lane >> 4;
  const int l16  = lane & 15;

  // staging coords for this thread (4 issues of 16B each per operand)
  const int srow = tid >> 3;        // +i*32 per issue
  const int sc   = (tid & 7) * 8;   // u16 col

  f32x4 acc[4][4];
#pragma unroll
  for (int m = 0; m < 4; ++m)
#pragma unroll
    for (int n = 0; n < 4; ++n) acc[m][n] = f32x4{0.f, 0.f, 0.f, 0.f};

  for (int kt = 0; kt < 1024; kt += 64) {
    const u16* Ab = A + (long)(brow + srow) * LD + kt + sc;
    const u16* Bb = Bt + (long)(bcol + srow) * LD + kt + sc;
#pragma unroll
    for (int i = 0; i < 4; ++i) {
      gld_lds16(Ab + (long)i * 32 * LD, As + (i * 256 + tid) * 8);
      gld_lds16(Bb + (long)i * 32 * LD, Bs + (i * 256 + tid) * 8);
    }
    __syncthreads();
#pragma unroll
    for (int kk = 0; kk < 2; ++kk) {
      bf16x8 af[4], bfr[4];
#pragma unroll
      for (int m = 0; m < 4; ++m)
        af[m] = *(const bf16x8*)(As + (wr * 64 + m * 16 + l16) * 64 + kk * 32 + kgrp * 8);
#pragma unroll
      for (int n = 0; n < 4; ++n)
        bfr[n] = *(const bf16x8*)(Bs + (wc * 64 + n * 16 + l16) * 64 + kk * 32 + kgrp * 8);
#pragma unroll
      for (int m = 0; m < 4; ++m)
#pragma unroll
        for (int n = 0; n < 4; ++n)
          acc[m][n] = __builtin_amdgcn_mfma_f32_16x16x32_bf16(af[m], bfr[n], acc[m][n], 0, 0, 0);
    }
    __syncthreads();
  }

#pragma unroll
  for (int m = 0; m < 4; ++m) {
    const int gr0 = brow + wr * 64 + m * 16 + kgrp * 4;
#pragma unroll
    for (int n = 0; n < 4; ++n) {
      const int gc = bcol + wc * 64 + n * 16 + l16;
      if constexpr (OUT_F32) {
        float* C = (float*)C_;
        const float bv = BIAS ? bias[gc] : 0.0f;
#pragma unroll
        for (int j = 0; j < 4; ++j)
          C[(long)(gr0 + j) * LD + gc] = acc[m][n][j] + bv;
      } else {
        u16* C = (u16*)C_;
#pragma unroll
        for (int j = 0; j < 4; ++j)
          C[(long)(gr0 + j) * LD + gc] = f2bf(acc[m][n][j]);
        if constexpr (WRITE_T) {
          u16x4 t;
#pragma unroll
          for (int j = 0; j < 4; ++j) t[j] = f2bf(acc[m][n][j]);
          long ti = ((long)(gc >> 7) * 32 + (gr0 >> 9)) * 65536 + (long)(gc & 127) * 512 + (gr0 & 511);
          *(u16x4*)(Ct + ti) = t;
        }
      }
    }
  }
}

// ---------------------------------------------------------------------------
// Fused attention: scores (QK^T), softmax, score write (f32, output), and
// ctx = P @ kx via kxT (PV fused, P transposed through per-wave LDS).
// One block = (h, b, 64 q-rows).  4 waves x 16 q-rows.
// LDS union (34816 B total):
//   QK^T staging view: Ks[64][136]               (8704 u16)
//   PV view:           P[4 waves][16][272]       (17408 u16)  <- sized in u16!
// Pitch 272 u16 = 544 B: 16B-aligned rows (b128 reads), 136 dwords/row
// (not 0 mod 32) so column-slice reads spread across banks.
// ---------------------------------------------------------------------------
__global__ __launch_bounds__(256)
void attn_fused(const u16* __restrict__ qx, const u16* __restrict__ kx,
                const u16* __restrict__ kxT,
                float* __restrict__ score, u16* __restrict__ ctx)
{
  __shared__ __align__(16) u16 lds[4 * 16 * 272];   // 34816 bytes
  u16 (*Ks)[136] = (u16(*)[136])lds;
  const int tid = threadIdx.x, lane = tid & 63, w = tid >> 6;
  const int bid = blockIdx.x;
  const int qt = bid & 7, hb = bid >> 3, h = hb >> 5, b = hb & 31;
  const int kgrp = lane >> 4, l16 = lane & 15;

  // Q fragments (16 q-rows per wave)
  const u16* qrow = qx + ((long)(b * 512 + qt * 64 + w * 16 + l16)) * 1024 + h * 128 + kgrp * 8;
  bf16x8 qf[4];
#pragma unroll
  for (int kk = 0; kk < 4; ++kk) qf[kk] = *(const bf16x8*)(qrow + kk * 32);

  f32x4 acc[32];
#pragma unroll
  for (int n = 0; n < 32; ++n) acc[n] = f32x4{0.f, 0.f, 0.f, 0.f};

  const u16* kbase = kx + (long)b * 512 * 1024 + h * 128;
  for (int chunk = 0; chunk < 8; ++chunk) {
    __syncthreads();
#pragma unroll
    for (int i = 0; i < 4; ++i) {
      int idx = i * 256 + tid;
      int row = idx >> 4, c8 = idx & 15;
      *(u16x8*)(&Ks[row][c8 * 8]) =
          *(const u16x8*)(kbase + (long)(chunk * 64 + row) * 1024 + c8 * 8);
    }
    __syncthreads();
#pragma unroll
    for (int kk = 0; kk < 4; ++kk)
#pragma unroll
      for (int nl = 0; nl < 4; ++nl) {
        bf16x8 bfr = *(const bf16x8*)(&Ks[nl * 16 + l16][kk * 32 + kgrp * 8]);
        acc[chunk * 4 + nl] =
            __builtin_amdgcn_mfma_f32_16x16x32_bf16(qf[kk], bfr, acc[chunk * 4 + nl], 0, 0, 0);
      }
  }

  // softmax (rows r = kgrp*4+j spread over 16-lane column groups)
  const float scale = 0.08838834764831845f;  // 1/sqrt(128)
#pragma unroll
  for (int j = 0; j < 4; ++j) {
    float m = -1e30f;
#pragma unroll
    for (int n = 0; n < 32; ++n) m = fmaxf(m, acc[n][j]);
    m = fmaxf(m, __shfl_xor(m, 1));
    m = fmaxf(m, __shfl_xor(m, 2));
    m = fmaxf(m, __shfl_xor(m, 4));
    m = fmaxf(m, __shfl_xor(m, 8));
    float s = 0.f;
#pragma unroll
    for (int n = 0; n < 32; ++n) {
      float e = __expf((acc[n][j] - m) * scale);
      acc[n][j] = e; s += e;
    }
    s += __shfl_xor(s, 1);
    s += __shfl_xor(s, 2);
    s += __shfl_xor(s, 4);
    s += __shfl_xor(s, 8);
    float inv = 1.0f / s;
#pragma unroll
    for (int n = 0; n < 32; ++n) acc[n][j] *= inv;
  }

  // score write (f32 output, mandatory)
  float* srow = score + ((long)hb * 512 + qt * 64 + w * 16 + kgrp * 4) * 512 + l16;
#pragma unroll
  for (int j = 0; j < 4; ++j)
#pragma unroll
    for (int n = 0; n < 32; ++n)
      srow[(long)j * 512 + n * 16] = acc[n][j];

  // ---- PV: ctx(16 q x 128 d per wave) = P @ kx, K=512 in two halves ----
  u16* Pw = lds + w * 16 * 272;   // per-wave [16][272] bf16
  f32x4 acc2[8];
#pragma unroll
  for (int n = 0; n < 8; ++n) acc2[n] = f32x4{0.f, 0.f, 0.f, 0.f};
  const u16* kxTb = kxT + (long)hb * 65536;

  for (int h2 = 0; h2 < 2; ++h2) {
    __syncthreads();   // Ks reads / previous-half P reads complete
#pragma unroll
    for (int j = 0; j < 4; ++j)
#pragma unroll
      for (int nn = 0; nn < 16; ++nn)
        Pw[(kgrp * 4 + j) * 272 + l16 + nn * 16] = f2bf(acc[h2 * 16 + nn][j]);
    __syncthreads();
#pragma unroll
    for (int ks = 0; ks < 8; ++ks) {
      bf16x8 pa = *(const bf16x8*)(Pw + l16 * 272 + ks * 32 + kgrp * 8);
      const u16* bbase = kxTb + (long)l16 * 512 + h2 * 256 + ks * 32 + kgrp * 8;
#pragma unroll
      for (int n = 0; n < 8; ++n) {
        bf16x8 bb = *(const bf16x8*)(bbase + (long)n * 16 * 512);
        acc2[n] = __builtin_amdgcn_mfma_f32_16x16x32_bf16(pa, bb, acc2[n], 0, 0, 0);
      }
    }
  }

  // ctx write: (b, q, h*128 + d) bf16
  u16* crow = ctx + ((long)(b * 512 + qt * 64 + w * 16 + kgrp * 4)) * 1024 + h * 128 + l16;
#pragma unroll
  for (int n = 0; n < 8; ++n)
#pragma unroll
    for (int j = 0; j < 4; ++j)
      crow[(long)j * 1024 + n * 16] = f2bf(acc2[n][j]);
}

// ---------------------------------------------------------------------------
// Packing kernels
// ---------------------------------------------------------------------------
// straight f32 -> bf16 convert, 4 elems/thread
__global__ __launch_bounds__(256)
void pack_bf16(const float4* __restrict__ in, u16x4* __restrict__ o)
{
  long i = (long)blockIdx.x * 256 + threadIdx.x;
  float4 v = in[i];
  u16x4 t;
  t[0] = f2bf(v.x); t[1] = f2bf(v.y); t[2] = f2bf(v.z); t[3] = f2bf(v.w);
  o[i] = t;
}

// w (H=8, E=1024, D=128) f32 -> wT[(h*128+d)*1024 + e] bf16
__global__ __launch_bounds__(256)
void pack_whead(const float* __restrict__ w, u16* __restrict__ wT)
{
  long i = (long)blockIdx.x * 256 + threadIdx.x;   // i = n*1024 + e
  int n = (int)(i >> 10), e = (int)(i & 1023);
  int h = n >> 7, d = n & 127;
  wT[i] = f2bf(w[((long)h * 1024 + e) * 128 + d]);
}

// ---------------------------------------------------------------------------
extern "C" void kernel_launch(void* const* d_in, const int* in_sizes, int n_in,
                              void* d_out, int out_size, void* d_ws, size_t ws_size,
                              hipStream_t stream)
{
  const float* k      = (const float*)d_in[0];
  const float* q      = (const float*)d_in[1];
  const float* w_kx   = (const float*)d_in[2];
  const float* w_qx   = (const float*)d_in[3];
  const float* proj_w = (const float*)d_in[4];
  const float* proj_b = (const float*)d_in[5];

  float* out   = (float*)d_out;                  // 16777216 f32
  float* score = (float*)d_out + 16777216;       // 67108864 f32

  char* ws = (char*)d_ws;
  u16* wkT = (u16*)(ws + 0);                     // 2 MB
  u16* wqT = (u16*)(ws + (2l << 20));            // 2 MB
  u16* pwB = (u16*)(ws + (4l << 20));            // 2 MB
  u16* kbf = (u16*)(ws + 6291456l);              // 33.55 MB  k bf16
  u16* qbf = (u16*)(ws + 39845888l);             // 33.55 MB  q bf16
  u16* kx  = (u16*)(ws + 73400320l);             // 33.55 MB  (b,kl,h*128+d)
  u16* qx  = (u16*)(ws + 106954752l);            // 33.55 MB
  u16* kxT = (u16*)(ws + 140509184l);            // 33.55 MB  (hb,d,kl)
  u16* ctx = kbf;                                // kbf dead after gemm K

  // 1) packs
  pack_bf16<<<16384, 256, 0, stream>>>((const float4*)k, (u16x4*)kbf);
  pack_bf16<<<16384, 256, 0, stream>>>((const float4*)q, (u16x4*)qbf);
  pack_bf16<<<1024, 256, 0, stream>>>((const float4*)proj_w, (u16x4*)pwB);
  pack_whead<<<4096, 256, 0, stream>>>(w_kx, wkT);
  pack_whead<<<4096, 256, 0, stream>>>(w_qx, wqT);

  // 2) projections: kx = k @ wkT^T (also kxT); qx = q @ wqT^T
  gemm_bt16<false, true, false><<<dim3(8, 128), 256, 0, stream>>>(kbf, wkT, kx, kxT, nullptr);
  gemm_bt16<false, false, false><<<dim3(8, 128), 256, 0, stream>>>(qbf, wqT, qx, nullptr, nullptr);

  // 3) fused scores + softmax + PV
  attn_fused<<<2048, 256, 0, stream>>>(qx, kx, kxT, score, ctx);

  // 4) out = ctx @ proj_w^T + b
  gemm_bt16<true, false, true><<<dim3(8, 128), 256, 0, stream>>>(ctx, pwB, out, nullptr, proj_b);
}

// Round 6
// 835.320 us; speedup vs baseline: 1.0549x; 1.0549x over previous
//
#include <hip/hip_runtime.h>

typedef unsigned short u16;
typedef unsigned int u32;
typedef u16 u16x4 __attribute__((ext_vector_type(4)));
typedef u16 u16x8 __attribute__((ext_vector_type(8)));
typedef short bf16x8 __attribute__((ext_vector_type(8)));
typedef float f32x4 __attribute__((ext_vector_type(4)));

static __device__ __forceinline__ u16 f2bf(float f) {
  union { float f; unsigned u; } v; v.f = f;
  unsigned r = v.u + 0x7FFFu + ((v.u >> 16) & 1u);
  return (u16)(r >> 16);
}

// async global->LDS, 16B per lane (dest must be linear: wave base + lane*16)
static __device__ __forceinline__ void gld_lds16(const u16* g, u16* l) {
  __builtin_amdgcn_global_load_lds(
      (const __attribute__((address_space(1))) u32*)g,
      (__attribute__((address_space(3))) u32*)l, 16, 0, 0);
}

// Problem constants: B=32, L=512, E=1024, H=8, D=128, OUT=1024
// score: (H*B, 512, 512) head-major.  ctx: (B, 512, H*128)

// ---------------------------------------------------------------------------
// bf16 GEMM: C = A @ Bt^T.  A: 16384x1024 row-major (f32 w/ inline convert,
// or bf16 via global_load_lds).  Bt: 1024x1024 bf16.  Tile 128x128, BK=64,
// 4 waves (2x2).  1-D grid 1024 with XCD-locality swizzle: the 8 col-blocks
// sharing an A row-slab run consecutively on ONE XCD (A fetched once/slab).
// ---------------------------------------------------------------------------
template<bool A_F32, bool OUT_F32, bool WRITE_T, bool BIAS>
__global__ __launch_bounds__(256)
void gemm_bt16(const void* __restrict__ A_, const u16* __restrict__ Bt,
               void* __restrict__ C_, u16* __restrict__ Ct,
               const float* __restrict__ bias)
{
  constexpr int LD = 1024;
  __shared__ __align__(16) u16 As[128 * 64];
  __shared__ __align__(16) u16 Bs[128 * 64];

  const int tid  = threadIdx.x;
  const int lane = tid & 63;
  const int w    = tid >> 6;
  const int wr   = w >> 1, wc = w & 1;
  // XCD swizzle: xcd = bid&7; 8 consecutive blocks on an XCD share one row-slab
  const int bid  = blockIdx.x;
  const int xcd  = bid & 7, t = bid >> 3;          // t in [0,128)
  const int bcol = (t & 7) * 128;
  const int brow = (xcd * 16 + (t >> 3)) * 128;    // rows [16*xcd,16*xcd+16)
  const int kgrp = lane >> 4;
  const int l16  = lane & 15;

  // bf16 staging coords (global_load_lds): 4 issues of 16B per operand
  const int srow = tid >> 3;        // +i*32 per issue
  const int sc   = (tid & 7) * 8;   // u16 col

  f32x4 acc[4][4];
#pragma unroll
  for (int m = 0; m < 4; ++m)
#pragma unroll
    for (int n = 0; n < 4; ++n) acc[m][n] = f32x4{0.f, 0.f, 0.f, 0.f};

  for (int kt = 0; kt < 1024; kt += 64) {
    if constexpr (A_F32) {
      const float* A = (const float*)A_;
#pragma unroll
      for (int i = 0; i < 4; ++i) {
        int idx = i * 256 + tid;          // row = idx>>3 (0..127), 8 granules of 8
        int row = idx >> 3, c8 = idx & 7;
        const float* src = A + (long)(brow + row) * LD + kt + c8 * 8;
        float4 v0 = *(const float4*)(src);
        float4 v1 = *(const float4*)(src + 4);
        u16x8 bb;
        bb[0] = f2bf(v0.x); bb[1] = f2bf(v0.y); bb[2] = f2bf(v0.z); bb[3] = f2bf(v0.w);
        bb[4] = f2bf(v1.x); bb[5] = f2bf(v1.y); bb[6] = f2bf(v1.z); bb[7] = f2bf(v1.w);
        *(u16x8*)(As + row * 64 + c8 * 8) = bb;
      }
    } else {
      const u16* A = (const u16*)A_;
      const u16* Ab = A + (long)(brow + srow) * LD + kt + sc;
#pragma unroll
      for (int i = 0; i < 4; ++i)
        gld_lds16(Ab + (long)i * 32 * LD, As + (i * 256 + tid) * 8);
    }
    const u16* Bb = Bt + (long)(bcol + srow) * LD + kt + sc;
#pragma unroll
    for (int i = 0; i < 4; ++i)
      gld_lds16(Bb + (long)i * 32 * LD, Bs + (i * 256 + tid) * 8);
    __syncthreads();
#pragma unroll
    for (int kk = 0; kk < 2; ++kk) {
      bf16x8 af[4], bfr[4];
#pragma unroll
      for (int m = 0; m < 4; ++m)
        af[m] = *(const bf16x8*)(As + (wr * 64 + m * 16 + l16) * 64 + kk * 32 + kgrp * 8);
#pragma unroll
      for (int n = 0; n < 4; ++n)
        bfr[n] = *(const bf16x8*)(Bs + (wc * 64 + n * 16 + l16) * 64 + kk * 32 + kgrp * 8);
#pragma unroll
      for (int m = 0; m < 4; ++m)
#pragma unroll
        for (int n = 0; n < 4; ++n)
          acc[m][n] = __builtin_amdgcn_mfma_f32_16x16x32_bf16(af[m], bfr[n], acc[m][n], 0, 0, 0);
    }
    __syncthreads();
  }

#pragma unroll
  for (int m = 0; m < 4; ++m) {
    const int gr0 = brow + wr * 64 + m * 16 + kgrp * 4;
#pragma unroll
    for (int n = 0; n < 4; ++n) {
      const int gc = bcol + wc * 64 + n * 16 + l16;
      if constexpr (OUT_F32) {
        float* C = (float*)C_;
        const float bv = BIAS ? bias[gc] : 0.0f;
#pragma unroll
        for (int j = 0; j < 4; ++j)
          C[(long)(gr0 + j) * LD + gc] = acc[m][n][j] + bv;
      } else {
        u16* C = (u16*)C_;
#pragma unroll
        for (int j = 0; j < 4; ++j)
          C[(long)(gr0 + j) * LD + gc] = f2bf(acc[m][n][j]);
        if constexpr (WRITE_T) {
          u16x4 tt;
#pragma unroll
          for (int j = 0; j < 4; ++j) tt[j] = f2bf(acc[m][n][j]);
          long ti = ((long)(gc >> 7) * 32 + (gr0 >> 9)) * 65536 + (long)(gc & 127) * 512 + (gr0 & 511);
          *(u16x4*)(Ct + ti) = tt;
        }
      }
    }
  }
}

// ---------------------------------------------------------------------------
// Fused attention: QK^T + softmax + score write (f32) + ctx = P @ kx (kxT).
// One block = (h, b, 64 q-rows), 4 waves x 16 q-rows.
// XCD swizzle: h = bid&7 (one head per XCD); the 8 qt-blocks sharing a
// (h,b) K-slab run consecutively on one XCD -> slab fetched once into its L2.
// K staging double-buffered (reg prefetch, 1 barrier/chunk).
// LDS union (34816 B): K dbuf [2][64][136] u16  |  P view [4][16][272] u16.
// Score stores issued per-half right after the P-transpose -> overlap PV MFMA.
// ---------------------------------------------------------------------------
__global__ __launch_bounds__(256, 3)
void attn_fused(const u16* __restrict__ qx, const u16* __restrict__ kx,
                const u16* __restrict__ kxT,
                float* __restrict__ score, u16* __restrict__ ctx)
{
  __shared__ __align__(16) u16 lds[2 * 64 * 136];   // 34816 bytes
  const int tid = threadIdx.x, lane = tid & 63, w = tid >> 6;
  const int bid = blockIdx.x;
  const int xcd = bid & 7, t = bid >> 3;   // t in [0,256)
  const int qt = t & 7;
  const int h  = xcd;
  const int b  = t >> 3;                   // [0,32)
  const int hb = h * 32 + b;
  const int kgrp = lane >> 4, l16 = lane & 15;

  // Q fragments (16 q-rows per wave)
  const u16* qrow = qx + ((long)(b * 512 + qt * 64 + w * 16 + l16)) * 1024 + h * 128 + kgrp * 8;
  bf16x8 qf[4];
#pragma unroll
  for (int kk = 0; kk < 4; ++kk) qf[kk] = *(const bf16x8*)(qrow + kk * 32);

  f32x4 acc[32];
#pragma unroll
  for (int n = 0; n < 32; ++n) acc[n] = f32x4{0.f, 0.f, 0.f, 0.f};

  const u16* kbase = kx + (long)b * 512 * 1024 + h * 128;

  // prologue: stage chunk 0
  {
    u16x8 r[4];
#pragma unroll
    for (int i = 0; i < 4; ++i) {
      int idx = i * 256 + tid;
      r[i] = *(const u16x8*)(kbase + (long)(idx >> 4) * 1024 + (idx & 15) * 8);
    }
#pragma unroll
    for (int i = 0; i < 4; ++i) {
      int idx = i * 256 + tid;
      *(u16x8*)(lds + (idx >> 4) * 136 + (idx & 15) * 8) = r[i];
    }
  }
  __syncthreads();

  for (int c = 0; c < 8; ++c) {
    u16x8 nxt[4];
    if (c < 7) {
#pragma unroll
      for (int i = 0; i < 4; ++i) {
        int idx = i * 256 + tid;
        nxt[i] = *(const u16x8*)(kbase + (long)((c + 1) * 64 + (idx >> 4)) * 1024 + (idx & 15) * 8);
      }
    }
    const u16* Kb = lds + (c & 1) * 8704;
#pragma unroll
    for (int kk = 0; kk < 4; ++kk)
#pragma unroll
      for (int nl = 0; nl < 4; ++nl) {
        bf16x8 bfr = *(const bf16x8*)(Kb + (nl * 16 + l16) * 136 + kk * 32 + kgrp * 8);
        acc[c * 4 + nl] =
            __builtin_amdgcn_mfma_f32_16x16x32_bf16(qf[kk], bfr, acc[c * 4 + nl], 0, 0, 0);
      }
    if (c < 7) {
      u16* Kn = lds + ((c + 1) & 1) * 8704;
#pragma unroll
      for (int i = 0; i < 4; ++i) {
        int idx = i * 256 + tid;
        *(u16x8*)(Kn + (idx >> 4) * 136 + (idx & 15) * 8) = nxt[i];
      }
    }
    __syncthreads();
  }

  // softmax (rows r = kgrp*4+j spread over 16-lane column groups)
  const float scale = 0.08838834764831845f;  // 1/sqrt(128)
#pragma unroll
  for (int j = 0; j < 4; ++j) {
    float m = -1e30f;
#pragma unroll
    for (int n = 0; n < 32; ++n) m = fmaxf(m, acc[n][j]);
    m = fmaxf(m, __shfl_xor(m, 1));
    m = fmaxf(m, __shfl_xor(m, 2));
    m = fmaxf(m, __shfl_xor(m, 4));
    m = fmaxf(m, __shfl_xor(m, 8));
    float s = 0.f;
#pragma unroll
    for (int n = 0; n < 32; ++n) {
      float e = __expf((acc[n][j] - m) * scale);
      acc[n][j] = e; s += e;
    }
    s += __shfl_xor(s, 1);
    s += __shfl_xor(s, 2);
    s += __shfl_xor(s, 4);
    s += __shfl_xor(s, 8);
    float inv = 1.0f / s;
#pragma unroll
    for (int n = 0; n < 32; ++n) acc[n][j] *= inv;
  }

  // ---- PV with per-half P transpose; score stores overlap PV MFMAs ----
  u16* Pw = lds + w * 16 * 272;   // per-wave [16][272] bf16 view of the union
  f32x4 acc2[8];
#pragma unroll
  for (int n = 0; n < 8; ++n) acc2[n] = f32x4{0.f, 0.f, 0.f, 0.f};
  const u16* kxTb = kxT + (long)hb * 65536;
  float* srow = score + ((long)hb * 512 + qt * 64 + w * 16 + kgrp * 4) * 512 + l16;

  for (int h2 = 0; h2 < 2; ++h2) {
    __syncthreads();   // prior LDS reads (QK^T / previous-half pa) complete
#pragma unroll
    for (int j = 0; j < 4; ++j)
#pragma unroll
      for (int nn = 0; nn < 16; ++nn)
        Pw[(kgrp * 4 + j) * 272 + l16 + nn * 16] = f2bf(acc[h2 * 16 + nn][j]);
    __syncthreads();
    // score stores for this half (this half of acc is dead afterwards)
#pragma unroll
    for (int j = 0; j < 4; ++j)
#pragma unroll
      for (int nn = 0; nn < 16; ++nn)
        srow[(long)j * 512 + (h2 * 16 + nn) * 16] = acc[h2 * 16 + nn][j];
#pragma unroll
    for (int ks = 0; ks < 8; ++ks) {
      bf16x8 pa = *(const bf16x8*)(Pw + l16 * 272 + ks * 32 + kgrp * 8);
      const u16* bbase = kxTb + (long)l16 * 512 + h2 * 256 + ks * 32 + kgrp * 8;
#pragma unroll
      for (int n = 0; n < 8; ++n) {
        bf16x8 bb = *(const bf16x8*)(bbase + (long)n * 16 * 512);
        acc2[n] = __builtin_amdgcn_mfma_f32_16x16x32_bf16(pa, bb, acc2[n], 0, 0, 0);
      }
    }
  }

  // ctx write: (b, q, h*128 + d) bf16
  u16* crow = ctx + ((long)(b * 512 + qt * 64 + w * 16 + kgrp * 4)) * 1024 + h * 128 + l16;
#pragma unroll
  for (int n = 0; n < 8; ++n)
#pragma unroll
    for (int j = 0; j < 4; ++j)
      crow[(long)j * 1024 + n * 16] = f2bf(acc2[n][j]);
}

// ---------------------------------------------------------------------------
// Packing kernels (weights only)
// ---------------------------------------------------------------------------
__global__ __launch_bounds__(256)
void pack_bf16(const float4* __restrict__ in, u16x4* __restrict__ o)
{
  long i = (long)blockIdx.x * 256 + threadIdx.x;
  float4 v = in[i];
  u16x4 t;
  t[0] = f2bf(v.x); t[1] = f2bf(v.y); t[2] = f2bf(v.z); t[3] = f2bf(v.w);
  o[i] = t;
}

// w (H=8, E=1024, D=128) f32 -> wT[(h*128+d)*1024 + e] bf16
__global__ __launch_bounds__(256)
void pack_whead(const float* __restrict__ w, u16* __restrict__ wT)
{
  long i = (long)blockIdx.x * 256 + threadIdx.x;   // i = n*1024 + e
  int n = (int)(i >> 10), e = (int)(i & 1023);
  int h = n >> 7, d = n & 127;
  wT[i] = f2bf(w[((long)h * 1024 + e) * 128 + d]);
}

// ---------------------------------------------------------------------------
extern "C" void kernel_launch(void* const* d_in, const int* in_sizes, int n_in,
                              void* d_out, int out_size, void* d_ws, size_t ws_size,
                              hipStream_t stream)
{
  const float* k      = (const float*)d_in[0];
  const float* q      = (const float*)d_in[1];
  const float* w_kx   = (const float*)d_in[2];
  const float* w_qx   = (const float*)d_in[3];
  const float* proj_w = (const float*)d_in[4];
  const float* proj_b = (const float*)d_in[5];

  float* out   = (float*)d_out;                  // 16777216 f32
  float* score = (float*)d_out + 16777216;       // 67108864 f32

  char* ws = (char*)d_ws;
  u16* wkT = (u16*)(ws + 0);                     // 2 MB
  u16* wqT = (u16*)(ws + (2l << 20));            // 2 MB
  u16* pwB = (u16*)(ws + (4l << 20));            // 2 MB
  u16* kx  = (u16*)(ws + 6291456l);              // 33.55 MB  (b,kl,h*128+d)
  u16* qx  = (u16*)(ws + 39845888l);             // 33.55 MB
  u16* kxT = (u16*)(ws + 73400320l);             // 33.55 MB  (hb,d,kl)
  u16* ctx = (u16*)(ws + 106954752l);            // 33.55 MB  (b,q,h*128+d)

  // 1) weight packs
  pack_bf16<<<1024, 256, 0, stream>>>((const float4*)proj_w, (u16x4*)pwB);
  pack_whead<<<4096, 256, 0, stream>>>(w_kx, wkT);
  pack_whead<<<4096, 256, 0, stream>>>(w_qx, wqT);

  // 2) projections straight from f32 inputs: kx = k @ wkT^T (+kxT); qx = q @ wqT^T
  gemm_bt16<true, false, true, false><<<1024, 256, 0, stream>>>(k, wkT, kx, kxT, nullptr);
  gemm_bt16<true, false, false, false><<<1024, 256, 0, stream>>>(q, wqT, qx, nullptr, nullptr);

  // 3) fused scores + softmax + PV
  attn_fused<<<2048, 256, 0, stream>>>(qx, kx, kxT, score, ctx);

  // 4) out = ctx @ proj_w^T + b
  gemm_bt16<false, true, false, true><<<1024, 256, 0, stream>>>(ctx, pwB, out, nullptr, proj_b);
}